// Round 17
// baseline (288.359 us; speedup 1.0000x reference)
//
#include <hip/hip_runtime.h>
#include <hip/hip_bf16.h>

#define D 64
#define MAXNB 1024
#define BIN_T 512
#define BIN_CHUNK 8192
#define BIN_EPT (BIN_CHUNK / BIN_T)   // 16 edges per thread
#define BUCKET_BITS 9
#define BUCKET_SIZE 512
#define COL_MASK 0x3FFFF
#define ROW_SHIFT 18

static __device__ __forceinline__ float bf_lo(unsigned v) {
  return __uint_as_float(v << 16);
}
static __device__ __forceinline__ float bf_hi(unsigned v) {
  return __uint_as_float(v & 0xffff0000u);
}
static __device__ __forceinline__ unsigned pack_bf2(float a, float b) {
  __hip_bfloat16 x = __float2bfloat16(a);
  __hip_bfloat16 y = __float2bfloat16(b);
  unsigned short ux = *reinterpret_cast<unsigned short*>(&x);
  unsigned short uy = *reinterpret_cast<unsigned short*>(&y);
  return (unsigned)ux | ((unsigned)uy << 16);
}

// ------ convert: e0_bf = bf16(concat(user,item)); zero counts; build list --
__global__ __launch_bounds__(256) void convert_kernel(
    const float4* __restrict__ ue, const float4* __restrict__ ie,
    uint2* __restrict__ out, int nu4, int total4,
    int* __restrict__ counts, int nbp1,
    const int* __restrict__ ui, const int* __restrict__ pi,
    const int* __restrict__ ni, int* __restrict__ list, int batch, int nu) {
  int i = blockIdx.x * blockDim.x + threadIdx.x;
  if (i < nbp1) counts[i] = 0;
  if (i < batch) {
    list[3 * i] = ui[i];
    list[3 * i + 1] = nu + pi[i];
    list[3 * i + 2] = nu + ni[i];
  }
  if (i >= total4) return;
  float4 v = (i < nu4) ? ue[i] : ie[i - nu4];
  out[i] = make_uint2(pack_bf2(v.x, v.y), pack_bf2(v.z, v.w));
}

// ---------------- bucket histogram (bucket = row>>9, LDS-accumulated) -----
__global__ __launch_bounds__(256) void bucket_hist_kernel(
    const int* __restrict__ rows, int* __restrict__ counts, int nnz, int nb) {
  __shared__ int h[MAXNB];
  int t = threadIdx.x;
  for (int i = t; i < nb; i += 256) h[i] = 0;
  __syncthreads();
  for (int e = blockIdx.x * 256 + t; e < nnz; e += gridDim.x * 256)
    atomicAdd(&h[rows[e] >> BUCKET_BITS], 1);
  __syncthreads();
  for (int i = t; i < nb; i += 256)
    if (h[i]) atomicAdd(&counts[i], h[i]);
}

// ------- single-block scan of bucket counts -> base AND cursor ------------
__global__ __launch_bounds__(1024) void bucket_scan_kernel(
    const int* __restrict__ counts, int* __restrict__ base,
    int* __restrict__ cursor, int nb) {
  __shared__ int lds[1024];
  int t = threadIdx.x;
  int v = (t < nb) ? counts[t] : 0;
  lds[t] = v;
  __syncthreads();
  for (int off = 1; off < 1024; off <<= 1) {
    int add = (t >= off) ? lds[t - off] : 0;
    __syncthreads();
    lds[t] += add;
    __syncthreads();
  }
  if (t < nb) {
    base[t + 1] = lds[t];
    cursor[t + 1] = lds[t];
  }
  if (t == 0) {
    base[0] = 0;
    cursor[0] = 0;
  }
}

// ------- bin: LDS-staged; scatter into LDS, stream out coalesced ----------
// record: x = col | (row & 511) << 18 ; y = val bits
__global__ __launch_bounds__(BIN_T) void bin_kernel(
    const float* __restrict__ vals, const int* __restrict__ rows,
    const int* __restrict__ cols, int* __restrict__ cursor,
    int2* __restrict__ binned, int nnz, int nb) {
  __shared__ int lh[BIN_T];       // counts -> lds alloc cursor
  __shared__ int lstart[BIN_T];   // exclusive lds start per bucket
  __shared__ int gbase[BIN_T];    // global base - lstart (pos map)
  __shared__ int2 stage[BIN_CHUNK];
  int t = threadIdx.x;
  long long b0 = (long long)blockIdx.x * BIN_CHUNK;
  int end_e = (int)((b0 + BIN_CHUNK < (long long)nnz) ? b0 + BIN_CHUNK
                                                      : (long long)nnz);
  int cnt = end_e - (int)b0;
  lh[t] = 0;
  __syncthreads();
  // phase A: count, cache rows
  int r[BIN_EPT];
  #pragma unroll
  for (int k = 0; k < BIN_EPT; ++k) {
    int e = (int)b0 + k * BIN_T + t;
    if (e < end_e) {
      r[k] = rows[e];
      atomicAdd(&lh[r[k] >> BUCKET_BITS], 1);
    } else {
      r[k] = -1;
    }
  }
  __syncthreads();
  // phase B: in-block scan of counts; reserve global runs
  int c = (t < nb) ? lh[t] : 0;
  lstart[t] = c;
  __syncthreads();
  for (int off = 1; off < BIN_T; off <<= 1) {
    int add = (t >= off) ? lstart[t - off] : 0;
    __syncthreads();
    lstart[t] += add;
    __syncthreads();
  }
  int excl = lstart[t] - c;
  int g = (t < nb && c) ? atomicAdd(&cursor[t], c) : 0;
  __syncthreads();
  if (t < nb) {
    gbase[t] = g - excl;
    lh[t] = excl;       // lds allocation cursor
    lstart[t] = excl;   // exclusive starts for phase D search
  }
  __syncthreads();
  // phase C: scatter records into LDS stage
  #pragma unroll
  for (int k = 0; k < BIN_EPT; ++k) {
    int e = (int)b0 + k * BIN_T + t;
    if (e < end_e) {
      int pos = atomicAdd(&lh[r[k] >> BUCKET_BITS], 1);
      stage[pos] = make_int2((cols[e] & COL_MASK) |
                                 ((r[k] & (BUCKET_SIZE - 1)) << ROW_SHIFT),
                             __float_as_int(vals[e]));
    }
  }
  __syncthreads();
  // phase D: linear sweep, coalesced global stores
  for (int i = t; i < cnt; i += BIN_T) {
    int lo = 0, hi = nb - 1;
    while (lo < hi) {
      int mid = (lo + hi + 1) >> 1;
      if (lstart[mid] <= i) lo = mid; else hi = mid - 1;
    }
    binned[gbase[lo] + i] = stage[i];
  }
}

// ---------------- place: exact CSR within 512-row bucket + row_start ------
__global__ __launch_bounds__(512) void place_kernel(
    const int2* __restrict__ binned, const int* __restrict__ base,
    int2* __restrict__ edges, int* __restrict__ row_start, int nrows, int nb) {
  __shared__ int rh[BUCKET_SIZE];
  __shared__ int cur[BUCKET_SIZE];
  int b = blockIdx.x;
  int t = threadIdx.x;
  int start = base[b];
  int end = base[b + 1];
  int r0 = b << BUCKET_BITS;
  rh[t] = 0;
  __syncthreads();
  for (int i = start + t; i < end; i += 512)
    atomicAdd(&rh[((unsigned)binned[i].x) >> ROW_SHIFT], 1);
  __syncthreads();
  int myc = rh[t];
  for (int off = 1; off < 512; off <<= 1) {
    int add = (t >= off) ? rh[t - off] : 0;
    __syncthreads();
    rh[t] += add;
    __syncthreads();
  }
  int excl = rh[t] - myc;
  int r = r0 + t;
  if (r < nrows) row_start[r] = start + excl;
  if (b == nb - 1 && t == 0) row_start[nrows] = end;
  cur[t] = start + excl;
  __syncthreads();
  for (int i = start + t; i < end; i += 512) {
    int2 rec = binned[i];
    unsigned x = (unsigned)rec.x;
    int pos = atomicAdd(&cur[x >> ROW_SHIFT], 1);
    edges[pos] = make_int2((int)(x & COL_MASK), rec.y);
  }
}

// ---------------- SpMM bf16: wave per row; dwordx4 gathers ----------------
// 8 lanes per edge (uint4 = 8 dims/lane), 8 edges per instruction.
__global__ __launch_bounds__(256) void spmm_bf16_kernel(
    const int* __restrict__ row_start, const int2* __restrict__ edges,
    const uint4* __restrict__ src,  // 8 uint4 per row
    uint4* __restrict__ dst, int nrows) {
  int wid = (int)(((long long)blockIdx.x * blockDim.x + threadIdx.x) >> 6);
  if (wid >= nrows) return;
  int lane = threadIdx.x & 63;
  int sub = lane >> 3;   // edge slot 0..7
  int d8 = lane & 7;     // uint4 index within row
  int s = row_start[wid];
  int e = row_start[wid + 1];
  float a0 = 0.f, a1 = 0.f, a2 = 0.f, a3 = 0.f;
  float a4 = 0.f, a5 = 0.f, a6 = 0.f, a7 = 0.f;
  int j = s;
  for (; j + 16 <= e; j += 16) {
    int2 E[2];
    uint4 V[2];
    #pragma unroll
    for (int k = 0; k < 2; ++k) E[k] = edges[j + 8 * k + sub];
    #pragma unroll
    for (int k = 0; k < 2; ++k)
      V[k] = src[((unsigned)E[k].x << 3) + (unsigned)d8];
    #pragma unroll
    for (int k = 0; k < 2; ++k) {
      float w = __int_as_float(E[k].y);
      a0 = fmaf(w, bf_lo(V[k].x), a0);
      a1 = fmaf(w, bf_hi(V[k].x), a1);
      a2 = fmaf(w, bf_lo(V[k].y), a2);
      a3 = fmaf(w, bf_hi(V[k].y), a3);
      a4 = fmaf(w, bf_lo(V[k].z), a4);
      a5 = fmaf(w, bf_hi(V[k].z), a5);
      a6 = fmaf(w, bf_lo(V[k].w), a6);
      a7 = fmaf(w, bf_hi(V[k].w), a7);
    }
  }
  // masked 8-edge tail iterations
  for (; j < e; j += 8) {
    int idx = j + sub;
    bool ok = idx < e;
    int2 ed = edges[ok ? idx : (e - 1)];
    uint4 v = src[((unsigned)ed.x << 3) + (unsigned)d8];
    float w = ok ? __int_as_float(ed.y) : 0.f;
    a0 = fmaf(w, bf_lo(v.x), a0);
    a1 = fmaf(w, bf_hi(v.x), a1);
    a2 = fmaf(w, bf_lo(v.y), a2);
    a3 = fmaf(w, bf_hi(v.y), a3);
    a4 = fmaf(w, bf_lo(v.z), a4);
    a5 = fmaf(w, bf_hi(v.z), a5);
    a6 = fmaf(w, bf_lo(v.w), a6);
    a7 = fmaf(w, bf_hi(v.w), a7);
  }
  #pragma unroll
  for (int off = 32; off >= 8; off >>= 1) {
    a0 += __shfl_down(a0, off, 64);
    a1 += __shfl_down(a1, off, 64);
    a2 += __shfl_down(a2, off, 64);
    a3 += __shfl_down(a3, off, 64);
    a4 += __shfl_down(a4, off, 64);
    a5 += __shfl_down(a5, off, 64);
    a6 += __shfl_down(a6, off, 64);
    a7 += __shfl_down(a7, off, 64);
  }
  if (lane < 8)
    dst[((unsigned)wid << 3) + (unsigned)d8] =
        make_uint4(pack_bf2(a0, a1), pack_bf2(a2, a3),
                   pack_bf2(a4, a5), pack_bf2(a6, a7));
}

// ---------------- SpMM bf16 over row list (layer 3) -----------------------
__global__ __launch_bounds__(256) void spmm_bf16_list_kernel(
    const int* __restrict__ row_start, const int2* __restrict__ edges,
    const uint4* __restrict__ src, uint4* __restrict__ dst,
    const int* __restrict__ list, int nlist) {
  int widx = (int)(((long long)blockIdx.x * blockDim.x + threadIdx.x) >> 6);
  if (widx >= nlist) return;
  int wid = list[widx];
  int lane = threadIdx.x & 63;
  int sub = lane >> 3;
  int d8 = lane & 7;
  int s = row_start[wid];
  int e = row_start[wid + 1];
  float a0 = 0.f, a1 = 0.f, a2 = 0.f, a3 = 0.f;
  float a4 = 0.f, a5 = 0.f, a6 = 0.f, a7 = 0.f;
  int j = s;
  for (; j + 16 <= e; j += 16) {
    int2 E[2];
    uint4 V[2];
    #pragma unroll
    for (int k = 0; k < 2; ++k) E[k] = edges[j + 8 * k + sub];
    #pragma unroll
    for (int k = 0; k < 2; ++k)
      V[k] = src[((unsigned)E[k].x << 3) + (unsigned)d8];
    #pragma unroll
    for (int k = 0; k < 2; ++k) {
      float w = __int_as_float(E[k].y);
      a0 = fmaf(w, bf_lo(V[k].x), a0);
      a1 = fmaf(w, bf_hi(V[k].x), a1);
      a2 = fmaf(w, bf_lo(V[k].y), a2);
      a3 = fmaf(w, bf_hi(V[k].y), a3);
      a4 = fmaf(w, bf_lo(V[k].z), a4);
      a5 = fmaf(w, bf_hi(V[k].z), a5);
      a6 = fmaf(w, bf_lo(V[k].w), a6);
      a7 = fmaf(w, bf_hi(V[k].w), a7);
    }
  }
  for (; j < e; j += 8) {
    int idx = j + sub;
    bool ok = idx < e;
    int2 ed = edges[ok ? idx : (e - 1)];
    uint4 v = src[((unsigned)ed.x << 3) + (unsigned)d8];
    float w = ok ? __int_as_float(ed.y) : 0.f;
    a0 = fmaf(w, bf_lo(v.x), a0);
    a1 = fmaf(w, bf_hi(v.x), a1);
    a2 = fmaf(w, bf_lo(v.y), a2);
    a3 = fmaf(w, bf_hi(v.y), a3);
    a4 = fmaf(w, bf_lo(v.z), a4);
    a5 = fmaf(w, bf_hi(v.z), a5);
    a6 = fmaf(w, bf_lo(v.w), a6);
    a7 = fmaf(w, bf_hi(v.w), a7);
  }
  #pragma unroll
  for (int off = 32; off >= 8; off >>= 1) {
    a0 += __shfl_down(a0, off, 64);
    a1 += __shfl_down(a1, off, 64);
    a2 += __shfl_down(a2, off, 64);
    a3 += __shfl_down(a3, off, 64);
    a4 += __shfl_down(a4, off, 64);
    a5 += __shfl_down(a5, off, 64);
    a6 += __shfl_down(a6, off, 64);
    a7 += __shfl_down(a7, off, 64);
  }
  if (lane < 8)
    dst[((unsigned)wid << 3) + (unsigned)d8] =
        make_uint4(pack_bf2(a0, a1), pack_bf2(a2, a3),
                   pack_bf2(a4, a5), pack_bf2(a6, a7));
}

// ---------------- score: 2 batch elems per wave; e0 from f32 inputs --------
__global__ __launch_bounds__(256) void score2_kernel(
    const float* __restrict__ ue, const float* __restrict__ ie,
    const unsigned* __restrict__ e1, const unsigned* __restrict__ e2,
    const unsigned* __restrict__ e3, const int* __restrict__ ui,
    const int* __restrict__ pi, const int* __restrict__ ni,
    float* __restrict__ out, int batch, int nu) {
  int w = (int)(((long long)blockIdx.x * blockDim.x + threadIdx.x) >> 6);
  int lane = threadIdx.x & 63;
  int half = lane >> 5;
  int d2 = lane & 31;
  int b = w * 2 + half;
  if (b >= batch) return;
  long long un = (long long)ui[b];
  int p = pi[b], n = ni[b];
  long long pn = (long long)(nu + p);
  long long nn_ = (long long)(nu + n);
  float2 U = *(const float2*)(ue + (un << 6) + (d2 << 1));
  float2 P = *(const float2*)(ie + ((long long)p << 6) + (d2 << 1));
  float2 Nv = *(const float2*)(ie + ((long long)n << 6) + (d2 << 1));
  unsigned v;
  v = e1[(un << 5) + d2]; U.x += bf_lo(v); U.y += bf_hi(v);
  v = e2[(un << 5) + d2]; U.x += bf_lo(v); U.y += bf_hi(v);
  v = e3[(un << 5) + d2]; U.x += bf_lo(v); U.y += bf_hi(v);
  v = e1[(pn << 5) + d2]; P.x += bf_lo(v); P.y += bf_hi(v);
  v = e2[(pn << 5) + d2]; P.x += bf_lo(v); P.y += bf_hi(v);
  v = e3[(pn << 5) + d2]; P.x += bf_lo(v); P.y += bf_hi(v);
  v = e1[(nn_ << 5) + d2]; Nv.x += bf_lo(v); Nv.y += bf_hi(v);
  v = e2[(nn_ << 5) + d2]; Nv.x += bf_lo(v); Nv.y += bf_hi(v);
  v = e3[(nn_ << 5) + d2]; Nv.x += bf_lo(v); Nv.y += bf_hi(v);
  float s = U.x * (P.x - Nv.x) + U.y * (P.y - Nv.y);
  #pragma unroll
  for (int off = 16; off; off >>= 1) s += __shfl_down(s, off, 32);
  if (d2 == 0) out[b] = s * (1.0f / 16.0f);
}

// ---------------- fallback path (f32 atomic scatter) ----------------
__global__ __launch_bounds__(256) void init_kernel(
    const float4* __restrict__ ue, const float4* __restrict__ ie,
    float4* __restrict__ e, float4* __restrict__ acc, int nu4, int total4) {
  int i = blockIdx.x * blockDim.x + threadIdx.x;
  if (i >= total4) return;
  float4 v = (i < nu4) ? ue[i] : ie[i - nu4];
  e[i] = v;
  acc[i] = v;
}

__global__ __launch_bounds__(256) void scatter_kernel(
    const float* __restrict__ vals, const int* __restrict__ rows,
    const int* __restrict__ cols, const float* __restrict__ src,
    float* __restrict__ dst, int nnz) {
  long long gid = (long long)blockIdx.x * blockDim.x + threadIdx.x;
  int e = (int)(gid >> 6);
  if (e >= nnz) return;
  int d = (int)(gid & 63);
  float w = vals[e];
  float x = src[((long long)cols[e] << 6) + d];
  atomicAdd(dst + (((long long)rows[e] << 6) + d), w * x);
}

__global__ __launch_bounds__(256) void acc_kernel(
    float4* __restrict__ acc, const float4* __restrict__ e, int total4) {
  int i = blockIdx.x * blockDim.x + threadIdx.x;
  if (i >= total4) return;
  float4 a = acc[i];
  float4 b = e[i];
  a.x += b.x; a.y += b.y; a.z += b.z; a.w += b.w;
  acc[i] = a;
}

__global__ __launch_bounds__(256) void score_kernel(
    const float* __restrict__ acc, const int* __restrict__ ui,
    const int* __restrict__ pi, const int* __restrict__ ni,
    float* __restrict__ out, int batch, int nu) {
  int wid = (int)(((long long)blockIdx.x * blockDim.x + threadIdx.x) >> 6);
  int lane = threadIdx.x & 63;
  if (wid >= batch) return;
  int u = ui[wid];
  int p = pi[wid];
  int n = ni[wid];
  float uv = acc[((long long)u << 6) + lane];
  float pv = acc[((long long)(nu + p) << 6) + lane];
  float nv = acc[((long long)(nu + n) << 6) + lane];
  float s = uv * (pv - nv);
  #pragma unroll
  for (int off = 32; off; off >>= 1) s += __shfl_down(s, off, 64);
  if (lane == 0) out[wid] = s * (1.0f / 16.0f);
}

static inline size_t align_up(size_t x) { return (x + 255) & ~(size_t)255; }

extern "C" void kernel_launch(void* const* d_in, const int* in_sizes, int n_in,
                              void* d_out, int out_size, void* d_ws, size_t ws_size,
                              hipStream_t stream) {
  const float* user_emb = (const float*)d_in[0];
  const float* item_emb = (const float*)d_in[1];
  const float* adj_vals = (const float*)d_in[2];
  const int* adj_rows = (const int*)d_in[3];
  const int* adj_cols = (const int*)d_in[4];
  const int* user_idx = (const int*)d_in[5];
  const int* pos_idx = (const int*)d_in[6];
  const int* neg_idx = (const int*)d_in[7];

  const int nnz = in_sizes[2];
  const int batch = in_sizes[5];
  const int nu = in_sizes[0] / D;
  const int ni = in_sizes[1] / D;
  const int nrows = nu + ni;
  const int nb = (nrows + BUCKET_SIZE - 1) / BUCKET_SIZE;  // 512-row buckets
  const long long nd = (long long)nrows * D;
  const size_t nd_bytes = (size_t)nd * sizeof(float);
  const size_t bf_tbl = align_up((size_t)nrows * D * 2);
  const size_t edges_bytes = align_up((size_t)nnz * 8);

  const int total4 = (int)(nd / 4);
  const int nu4 = nu * D / 4;
  const int ew_blocks = (total4 + 255) / 256;

  const size_t need = 4 * bf_tbl + 2 * edges_bytes +
                      align_up((size_t)(nrows + 1) * 4) +   // row_start
                      3 * align_up((size_t)(nb + 1) * 4) +  // base/counts/cursor
                      align_up((size_t)(3 * batch) * 4);    // list
  // fast path: col fits in 18 bits; bin's in-block scan needs nb <= BIN_T
  const bool fast = (ws_size >= need) && (nb <= BIN_T) && (nrows <= COL_MASK);

  if (fast) {
    char* wp = (char*)d_ws;
    unsigned* e0b = (unsigned*)wp;    wp += bf_tbl;
    unsigned* e1 = (unsigned*)wp;     wp += bf_tbl;
    unsigned* e2 = (unsigned*)wp;     wp += bf_tbl;
    unsigned* e3 = (unsigned*)wp;     wp += bf_tbl;
    int2* edges = (int2*)wp;          wp += edges_bytes;
    int2* binned = (int2*)wp;         wp += edges_bytes;
    int* row_start = (int*)wp;        wp += align_up((size_t)(nrows + 1) * 4);
    int* base = (int*)wp;             wp += align_up((size_t)(nb + 1) * 4);
    int* counts = (int*)wp;           wp += align_up((size_t)(nb + 1) * 4);
    int* cursor = (int*)wp;           wp += align_up((size_t)(nb + 1) * 4);
    int* list = (int*)wp;

    // e0 bf16 conversion (+ zero bucket counts, + layer-3 row list)
    convert_kernel<<<ew_blocks, 256, 0, stream>>>(
        (const float4*)user_emb, (const float4*)item_emb,
        (uint2*)e0b, nu4, total4, counts, nb + 1,
        user_idx, pos_idx, neg_idx, list, batch, nu);

    // bucket bases via LDS histogram + single-block scan (writes cursor too)
    bucket_hist_kernel<<<1024, 256, 0, stream>>>(adj_rows, counts, nnz, nb);
    bucket_scan_kernel<<<1, 1024, 0, stream>>>(counts, base, cursor, nb);

    // LDS-staged binning, then exact CSR placement
    bin_kernel<<<(nnz + BIN_CHUNK - 1) / BIN_CHUNK, BIN_T, 0, stream>>>(
        adj_vals, adj_rows, adj_cols, cursor, binned, nnz, nb);
    place_kernel<<<nb, 512, 0, stream>>>(binned, base, edges, row_start,
                                         nrows, nb);

    const int spmm_blocks = (nrows + 3) / 4;  // 4 waves/block
    spmm_bf16_kernel<<<spmm_blocks, 256, 0, stream>>>(
        row_start, edges, (const uint4*)e0b, (uint4*)e1, nrows);
    spmm_bf16_kernel<<<spmm_blocks, 256, 0, stream>>>(
        row_start, edges, (const uint4*)e1, (uint4*)e2, nrows);
    const int nlist = 3 * batch;
    spmm_bf16_list_kernel<<<(nlist + 3) / 4, 256, 0, stream>>>(
        row_start, edges, (const uint4*)e2, (uint4*)e3, list, nlist);

    score2_kernel<<<(batch / 2 + 3) / 4, 256, 0, stream>>>(
        user_emb, item_emb, e1, e2, e3, user_idx, pos_idx, neg_idx,
        (float*)d_out, batch, nu);
  } else {
    // fallback: f32 atomic scatter path (needs 3 * nd_bytes)
    char* wp = (char*)d_ws;
    float* acc = (float*)wp;          wp += nd_bytes;
    float* e_a = (float*)wp;          wp += nd_bytes;
    float* e_b = (float*)wp;

    init_kernel<<<ew_blocks, 256, 0, stream>>>(
        (const float4*)user_emb, (const float4*)item_emb,
        (float4*)e_a, (float4*)acc, nu4, total4);
    const long long scatter_work = (long long)nnz * 64;
    const int scatter_blocks = (int)((scatter_work + 255) / 256);
    float* src = e_a;
    float* dst = e_b;
    for (int layer = 0; layer < 3; ++layer) {
      hipMemsetAsync(dst, 0, nd_bytes, stream);
      scatter_kernel<<<scatter_blocks, 256, 0, stream>>>(adj_vals, adj_rows,
                                                         adj_cols, src, dst, nnz);
      acc_kernel<<<ew_blocks, 256, 0, stream>>>((float4*)acc, (const float4*)dst,
                                                total4);
      float* t = src; src = dst; dst = t;
    }
    score_kernel<<<(batch + 3) / 4, 256, 0, stream>>>(
        acc, user_idx, pos_idx, neg_idx, (float*)d_out, batch, nu);
  }
}

// Round 18
// 273.172 us; speedup vs baseline: 1.0556x; 1.0556x over previous
//
#include <hip/hip_runtime.h>
#include <hip/hip_bf16.h>

#define D 64
#define MAXNB 1024
#define BIN_T 1024
#define BIN_CHUNK 8192
#define BIN_EPT (BIN_CHUNK / BIN_T)   // 8 edges per thread
#define BUCKET_BITS 8
#define BUCKET_SIZE 256
#define COL_MASK 0x3FFFF
#define ROW_SHIFT 18

static __device__ __forceinline__ float bf_lo(unsigned v) {
  return __uint_as_float(v << 16);
}
static __device__ __forceinline__ float bf_hi(unsigned v) {
  return __uint_as_float(v & 0xffff0000u);
}
static __device__ __forceinline__ unsigned pack_bf2(float a, float b) {
  __hip_bfloat16 x = __float2bfloat16(a);
  __hip_bfloat16 y = __float2bfloat16(b);
  unsigned short ux = *reinterpret_cast<unsigned short*>(&x);
  unsigned short uy = *reinterpret_cast<unsigned short*>(&y);
  return (unsigned)ux | ((unsigned)uy << 16);
}

// ------ convert: e0_bf = bf16(concat(user,item)); zero counts; build list --
__global__ __launch_bounds__(256) void convert_kernel(
    const float4* __restrict__ ue, const float4* __restrict__ ie,
    uint2* __restrict__ out, int nu4, int total4,
    int* __restrict__ counts, int nbp1,
    const int* __restrict__ ui, const int* __restrict__ pi,
    const int* __restrict__ ni, int* __restrict__ list, int batch, int nu) {
  int i = blockIdx.x * blockDim.x + threadIdx.x;
  if (i < nbp1) counts[i] = 0;
  if (i < batch) {
    list[3 * i] = ui[i];
    list[3 * i + 1] = nu + pi[i];
    list[3 * i + 2] = nu + ni[i];
  }
  if (i >= total4) return;
  float4 v = (i < nu4) ? ue[i] : ie[i - nu4];
  out[i] = make_uint2(pack_bf2(v.x, v.y), pack_bf2(v.z, v.w));
}

// ---------------- bucket histogram (bucket = row>>8, LDS-accumulated) -----
__global__ __launch_bounds__(256) void bucket_hist_kernel(
    const int* __restrict__ rows, int* __restrict__ counts, int nnz, int nb) {
  __shared__ int h[MAXNB];
  int t = threadIdx.x;
  for (int i = t; i < nb; i += 256) h[i] = 0;
  __syncthreads();
  for (int e = blockIdx.x * 256 + t; e < nnz; e += gridDim.x * 256)
    atomicAdd(&h[rows[e] >> BUCKET_BITS], 1);
  __syncthreads();
  for (int i = t; i < nb; i += 256)
    if (h[i]) atomicAdd(&counts[i], h[i]);
}

// ------- single-block scan of bucket counts -> base AND cursor ------------
__global__ __launch_bounds__(1024) void bucket_scan_kernel(
    const int* __restrict__ counts, int* __restrict__ base,
    int* __restrict__ cursor, int nb) {
  __shared__ int lds[1024];
  int t = threadIdx.x;
  int v = (t < nb) ? counts[t] : 0;
  lds[t] = v;
  __syncthreads();
  for (int off = 1; off < 1024; off <<= 1) {
    int add = (t >= off) ? lds[t - off] : 0;
    __syncthreads();
    lds[t] += add;
    __syncthreads();
  }
  if (t < nb) {
    base[t + 1] = lds[t];
    cursor[t + 1] = lds[t];
  }
  if (t == 0) {
    base[0] = 0;
    cursor[0] = 0;
  }
}

// ------- bin: LDS-staged; scatter into LDS, stream out coalesced ----------
// record: x = col | (row & 255) << 18 ; y = val bits
__global__ __launch_bounds__(BIN_T) void bin_kernel(
    const float* __restrict__ vals, const int* __restrict__ rows,
    const int* __restrict__ cols, int* __restrict__ cursor,
    int2* __restrict__ binned, int nnz, int nb) {
  __shared__ int lh[BIN_T];       // counts -> lds alloc cursor
  __shared__ int lstart[BIN_T];   // exclusive lds start per bucket
  __shared__ int gbase[BIN_T];    // global base - lstart (pos map)
  __shared__ int2 stage[BIN_CHUNK];
  int t = threadIdx.x;
  long long b0 = (long long)blockIdx.x * BIN_CHUNK;
  int end_e = (int)((b0 + BIN_CHUNK < (long long)nnz) ? b0 + BIN_CHUNK
                                                      : (long long)nnz);
  int cnt = end_e - (int)b0;
  lh[t] = 0;
  __syncthreads();
  // phase A: count, cache rows
  int r[BIN_EPT];
  #pragma unroll
  for (int k = 0; k < BIN_EPT; ++k) {
    int e = (int)b0 + k * BIN_T + t;
    if (e < end_e) {
      r[k] = rows[e];
      atomicAdd(&lh[r[k] >> BUCKET_BITS], 1);
    } else {
      r[k] = -1;
    }
  }
  __syncthreads();
  // phase B: in-block scan of counts; reserve global runs
  int c = (t < nb) ? lh[t] : 0;
  lstart[t] = c;
  __syncthreads();
  for (int off = 1; off < BIN_T; off <<= 1) {
    int add = (t >= off) ? lstart[t - off] : 0;
    __syncthreads();
    lstart[t] += add;
    __syncthreads();
  }
  int excl = lstart[t] - c;
  int g = (t < nb && c) ? atomicAdd(&cursor[t], c) : 0;
  __syncthreads();
  if (t < nb) {
    gbase[t] = g - excl;
    lh[t] = excl;       // lds allocation cursor
    lstart[t] = excl;   // exclusive starts for phase D search
  }
  __syncthreads();
  // phase C: scatter records into LDS stage
  #pragma unroll
  for (int k = 0; k < BIN_EPT; ++k) {
    int e = (int)b0 + k * BIN_T + t;
    if (e < end_e) {
      int pos = atomicAdd(&lh[r[k] >> BUCKET_BITS], 1);
      stage[pos] = make_int2((cols[e] & COL_MASK) |
                                 ((r[k] & (BUCKET_SIZE - 1)) << ROW_SHIFT),
                             __float_as_int(vals[e]));
    }
  }
  __syncthreads();
  // phase D: linear sweep, coalesced global stores
  for (int i = t; i < cnt; i += BIN_T) {
    int lo = 0, hi = nb - 1;
    while (lo < hi) {
      int mid = (lo + hi + 1) >> 1;
      if (lstart[mid] <= i) lo = mid; else hi = mid - 1;
    }
    binned[gbase[lo] + i] = stage[i];
  }
}

// ---------------- place: exact CSR within 256-row bucket + row_start ------
__global__ __launch_bounds__(512) void place_kernel(
    const int2* __restrict__ binned, const int* __restrict__ base,
    int2* __restrict__ edges, int* __restrict__ row_start, int nrows, int nb) {
  __shared__ int rh[BUCKET_SIZE];
  __shared__ int cur[BUCKET_SIZE];
  int b = blockIdx.x;
  int t = threadIdx.x;
  int start = base[b];
  int end = base[b + 1];
  int r0 = b << BUCKET_BITS;
  if (t < BUCKET_SIZE) rh[t] = 0;
  __syncthreads();
  for (int i = start + t; i < end; i += 512)
    atomicAdd(&rh[((unsigned)binned[i].x) >> ROW_SHIFT], 1);
  __syncthreads();
  int myc = (t < BUCKET_SIZE) ? rh[t] : 0;
  for (int off = 1; off < BUCKET_SIZE; off <<= 1) {
    int add = (t >= off && t < BUCKET_SIZE) ? rh[t - off] : 0;
    __syncthreads();
    if (t < BUCKET_SIZE) rh[t] += add;
    __syncthreads();
  }
  if (t < BUCKET_SIZE) {
    int excl = rh[t] - myc;
    int r = r0 + t;
    if (r < nrows) row_start[r] = start + excl;
    if (b == nb - 1 && t == 0) row_start[nrows] = end;
    cur[t] = start + excl;
  }
  __syncthreads();
  for (int i = start + t; i < end; i += 512) {
    int2 rec = binned[i];
    unsigned x = (unsigned)rec.x;
    int pos = atomicAdd(&cur[x >> ROW_SHIFT], 1);
    edges[pos] = make_int2((int)(x & COL_MASK), rec.y);
  }
}

// ---------------- SpMM bf16: wave per row; dwordx4 gathers ----------------
// 8 lanes per edge (uint4 = 8 dims/lane), 8 edges per instruction.
__global__ __launch_bounds__(256) void spmm_bf16_kernel(
    const int* __restrict__ row_start, const int2* __restrict__ edges,
    const uint4* __restrict__ src,  // 8 uint4 per row
    uint4* __restrict__ dst, int nrows) {
  int wid = (int)(((long long)blockIdx.x * blockDim.x + threadIdx.x) >> 6);
  if (wid >= nrows) return;
  int lane = threadIdx.x & 63;
  int sub = lane >> 3;   // edge slot 0..7
  int d8 = lane & 7;     // uint4 index within row
  int s = row_start[wid];
  int e = row_start[wid + 1];
  float a0 = 0.f, a1 = 0.f, a2 = 0.f, a3 = 0.f;
  float a4 = 0.f, a5 = 0.f, a6 = 0.f, a7 = 0.f;
  int j = s;
  for (; j + 16 <= e; j += 16) {
    int2 E[2];
    uint4 V[2];
    #pragma unroll
    for (int k = 0; k < 2; ++k) E[k] = edges[j + 8 * k + sub];
    #pragma unroll
    for (int k = 0; k < 2; ++k)
      V[k] = src[((unsigned)E[k].x << 3) + (unsigned)d8];
    #pragma unroll
    for (int k = 0; k < 2; ++k) {
      float w = __int_as_float(E[k].y);
      a0 = fmaf(w, bf_lo(V[k].x), a0);
      a1 = fmaf(w, bf_hi(V[k].x), a1);
      a2 = fmaf(w, bf_lo(V[k].y), a2);
      a3 = fmaf(w, bf_hi(V[k].y), a3);
      a4 = fmaf(w, bf_lo(V[k].z), a4);
      a5 = fmaf(w, bf_hi(V[k].z), a5);
      a6 = fmaf(w, bf_lo(V[k].w), a6);
      a7 = fmaf(w, bf_hi(V[k].w), a7);
    }
  }
  // masked 8-edge tail iterations
  for (; j < e; j += 8) {
    int idx = j + sub;
    bool ok = idx < e;
    int2 ed = edges[ok ? idx : (e - 1)];
    uint4 v = src[((unsigned)ed.x << 3) + (unsigned)d8];
    float w = ok ? __int_as_float(ed.y) : 0.f;
    a0 = fmaf(w, bf_lo(v.x), a0);
    a1 = fmaf(w, bf_hi(v.x), a1);
    a2 = fmaf(w, bf_lo(v.y), a2);
    a3 = fmaf(w, bf_hi(v.y), a3);
    a4 = fmaf(w, bf_lo(v.z), a4);
    a5 = fmaf(w, bf_hi(v.z), a5);
    a6 = fmaf(w, bf_lo(v.w), a6);
    a7 = fmaf(w, bf_hi(v.w), a7);
  }
  #pragma unroll
  for (int off = 32; off >= 8; off >>= 1) {
    a0 += __shfl_down(a0, off, 64);
    a1 += __shfl_down(a1, off, 64);
    a2 += __shfl_down(a2, off, 64);
    a3 += __shfl_down(a3, off, 64);
    a4 += __shfl_down(a4, off, 64);
    a5 += __shfl_down(a5, off, 64);
    a6 += __shfl_down(a6, off, 64);
    a7 += __shfl_down(a7, off, 64);
  }
  if (lane < 8)
    dst[((unsigned)wid << 3) + (unsigned)d8] =
        make_uint4(pack_bf2(a0, a1), pack_bf2(a2, a3),
                   pack_bf2(a4, a5), pack_bf2(a6, a7));
}

// ---------------- SpMM bf16 over row list (layer 3) -----------------------
__global__ __launch_bounds__(256) void spmm_bf16_list_kernel(
    const int* __restrict__ row_start, const int2* __restrict__ edges,
    const uint4* __restrict__ src, uint4* __restrict__ dst,
    const int* __restrict__ list, int nlist) {
  int widx = (int)(((long long)blockIdx.x * blockDim.x + threadIdx.x) >> 6);
  if (widx >= nlist) return;
  int wid = list[widx];
  int lane = threadIdx.x & 63;
  int sub = lane >> 3;
  int d8 = lane & 7;
  int s = row_start[wid];
  int e = row_start[wid + 1];
  float a0 = 0.f, a1 = 0.f, a2 = 0.f, a3 = 0.f;
  float a4 = 0.f, a5 = 0.f, a6 = 0.f, a7 = 0.f;
  int j = s;
  for (; j + 16 <= e; j += 16) {
    int2 E[2];
    uint4 V[2];
    #pragma unroll
    for (int k = 0; k < 2; ++k) E[k] = edges[j + 8 * k + sub];
    #pragma unroll
    for (int k = 0; k < 2; ++k)
      V[k] = src[((unsigned)E[k].x << 3) + (unsigned)d8];
    #pragma unroll
    for (int k = 0; k < 2; ++k) {
      float w = __int_as_float(E[k].y);
      a0 = fmaf(w, bf_lo(V[k].x), a0);
      a1 = fmaf(w, bf_hi(V[k].x), a1);
      a2 = fmaf(w, bf_lo(V[k].y), a2);
      a3 = fmaf(w, bf_hi(V[k].y), a3);
      a4 = fmaf(w, bf_lo(V[k].z), a4);
      a5 = fmaf(w, bf_hi(V[k].z), a5);
      a6 = fmaf(w, bf_lo(V[k].w), a6);
      a7 = fmaf(w, bf_hi(V[k].w), a7);
    }
  }
  for (; j < e; j += 8) {
    int idx = j + sub;
    bool ok = idx < e;
    int2 ed = edges[ok ? idx : (e - 1)];
    uint4 v = src[((unsigned)ed.x << 3) + (unsigned)d8];
    float w = ok ? __int_as_float(ed.y) : 0.f;
    a0 = fmaf(w, bf_lo(v.x), a0);
    a1 = fmaf(w, bf_hi(v.x), a1);
    a2 = fmaf(w, bf_lo(v.y), a2);
    a3 = fmaf(w, bf_hi(v.y), a3);
    a4 = fmaf(w, bf_lo(v.z), a4);
    a5 = fmaf(w, bf_hi(v.z), a5);
    a6 = fmaf(w, bf_lo(v.w), a6);
    a7 = fmaf(w, bf_hi(v.w), a7);
  }
  #pragma unroll
  for (int off = 32; off >= 8; off >>= 1) {
    a0 += __shfl_down(a0, off, 64);
    a1 += __shfl_down(a1, off, 64);
    a2 += __shfl_down(a2, off, 64);
    a3 += __shfl_down(a3, off, 64);
    a4 += __shfl_down(a4, off, 64);
    a5 += __shfl_down(a5, off, 64);
    a6 += __shfl_down(a6, off, 64);
    a7 += __shfl_down(a7, off, 64);
  }
  if (lane < 8)
    dst[((unsigned)wid << 3) + (unsigned)d8] =
        make_uint4(pack_bf2(a0, a1), pack_bf2(a2, a3),
                   pack_bf2(a4, a5), pack_bf2(a6, a7));
}

// ---------------- score: 2 batch elems per wave; e0 from f32 inputs --------
__global__ __launch_bounds__(256) void score2_kernel(
    const float* __restrict__ ue, const float* __restrict__ ie,
    const unsigned* __restrict__ e1, const unsigned* __restrict__ e2,
    const unsigned* __restrict__ e3, const int* __restrict__ ui,
    const int* __restrict__ pi, const int* __restrict__ ni,
    float* __restrict__ out, int batch, int nu) {
  int w = (int)(((long long)blockIdx.x * blockDim.x + threadIdx.x) >> 6);
  int lane = threadIdx.x & 63;
  int half = lane >> 5;
  int d2 = lane & 31;
  int b = w * 2 + half;
  if (b >= batch) return;
  long long un = (long long)ui[b];
  int p = pi[b], n = ni[b];
  long long pn = (long long)(nu + p);
  long long nn_ = (long long)(nu + n);
  float2 U = *(const float2*)(ue + (un << 6) + (d2 << 1));
  float2 P = *(const float2*)(ie + ((long long)p << 6) + (d2 << 1));
  float2 Nv = *(const float2*)(ie + ((long long)n << 6) + (d2 << 1));
  unsigned v;
  v = e1[(un << 5) + d2]; U.x += bf_lo(v); U.y += bf_hi(v);
  v = e2[(un << 5) + d2]; U.x += bf_lo(v); U.y += bf_hi(v);
  v = e3[(un << 5) + d2]; U.x += bf_lo(v); U.y += bf_hi(v);
  v = e1[(pn << 5) + d2]; P.x += bf_lo(v); P.y += bf_hi(v);
  v = e2[(pn << 5) + d2]; P.x += bf_lo(v); P.y += bf_hi(v);
  v = e3[(pn << 5) + d2]; P.x += bf_lo(v); P.y += bf_hi(v);
  v = e1[(nn_ << 5) + d2]; Nv.x += bf_lo(v); Nv.y += bf_hi(v);
  v = e2[(nn_ << 5) + d2]; Nv.x += bf_lo(v); Nv.y += bf_hi(v);
  v = e3[(nn_ << 5) + d2]; Nv.x += bf_lo(v); Nv.y += bf_hi(v);
  float s = U.x * (P.x - Nv.x) + U.y * (P.y - Nv.y);
  #pragma unroll
  for (int off = 16; off; off >>= 1) s += __shfl_down(s, off, 32);
  if (d2 == 0) out[b] = s * (1.0f / 16.0f);
}

// ---------------- fallback path (f32 atomic scatter) ----------------
__global__ __launch_bounds__(256) void init_kernel(
    const float4* __restrict__ ue, const float4* __restrict__ ie,
    float4* __restrict__ e, float4* __restrict__ acc, int nu4, int total4) {
  int i = blockIdx.x * blockDim.x + threadIdx.x;
  if (i >= total4) return;
  float4 v = (i < nu4) ? ue[i] : ie[i - nu4];
  e[i] = v;
  acc[i] = v;
}

__global__ __launch_bounds__(256) void scatter_kernel(
    const float* __restrict__ vals, const int* __restrict__ rows,
    const int* __restrict__ cols, const float* __restrict__ src,
    float* __restrict__ dst, int nnz) {
  long long gid = (long long)blockIdx.x * blockDim.x + threadIdx.x;
  int e = (int)(gid >> 6);
  if (e >= nnz) return;
  int d = (int)(gid & 63);
  float w = vals[e];
  float x = src[((long long)cols[e] << 6) + d];
  atomicAdd(dst + (((long long)rows[e] << 6) + d), w * x);
}

__global__ __launch_bounds__(256) void acc_kernel(
    float4* __restrict__ acc, const float4* __restrict__ e, int total4) {
  int i = blockIdx.x * blockDim.x + threadIdx.x;
  if (i >= total4) return;
  float4 a = acc[i];
  float4 b = e[i];
  a.x += b.x; a.y += b.y; a.z += b.z; a.w += b.w;
  acc[i] = a;
}

__global__ __launch_bounds__(256) void score_kernel(
    const float* __restrict__ acc, const int* __restrict__ ui,
    const int* __restrict__ pi, const int* __restrict__ ni,
    float* __restrict__ out, int batch, int nu) {
  int wid = (int)(((long long)blockIdx.x * blockDim.x + threadIdx.x) >> 6);
  int lane = threadIdx.x & 63;
  if (wid >= batch) return;
  int u = ui[wid];
  int p = pi[wid];
  int n = ni[wid];
  float uv = acc[((long long)u << 6) + lane];
  float pv = acc[((long long)(nu + p) << 6) + lane];
  float nv = acc[((long long)(nu + n) << 6) + lane];
  float s = uv * (pv - nv);
  #pragma unroll
  for (int off = 32; off; off >>= 1) s += __shfl_down(s, off, 64);
  if (lane == 0) out[wid] = s * (1.0f / 16.0f);
}

static inline size_t align_up(size_t x) { return (x + 255) & ~(size_t)255; }

extern "C" void kernel_launch(void* const* d_in, const int* in_sizes, int n_in,
                              void* d_out, int out_size, void* d_ws, size_t ws_size,
                              hipStream_t stream) {
  const float* user_emb = (const float*)d_in[0];
  const float* item_emb = (const float*)d_in[1];
  const float* adj_vals = (const float*)d_in[2];
  const int* adj_rows = (const int*)d_in[3];
  const int* adj_cols = (const int*)d_in[4];
  const int* user_idx = (const int*)d_in[5];
  const int* pos_idx = (const int*)d_in[6];
  const int* neg_idx = (const int*)d_in[7];

  const int nnz = in_sizes[2];
  const int batch = in_sizes[5];
  const int nu = in_sizes[0] / D;
  const int ni = in_sizes[1] / D;
  const int nrows = nu + ni;
  const int nb = (nrows + BUCKET_SIZE - 1) / BUCKET_SIZE;  // 256-row buckets
  const long long nd = (long long)nrows * D;
  const size_t nd_bytes = (size_t)nd * sizeof(float);
  const size_t bf_tbl = align_up((size_t)nrows * D * 2);
  const size_t edges_bytes = align_up((size_t)nnz * 8);

  const int total4 = (int)(nd / 4);
  const int nu4 = nu * D / 4;
  const int ew_blocks = (total4 + 255) / 256;

  const size_t need = 4 * bf_tbl + 2 * edges_bytes +
                      align_up((size_t)(nrows + 1) * 4) +   // row_start
                      3 * align_up((size_t)(nb + 1) * 4) +  // base/counts/cursor
                      align_up((size_t)(3 * batch) * 4);    // list
  // fast path: col fits in 18 bits; bin's in-block scan needs nb <= BIN_T
  const bool fast = (ws_size >= need) && (nb <= BIN_T) && (nrows <= COL_MASK);

  if (fast) {
    char* wp = (char*)d_ws;
    unsigned* e0b = (unsigned*)wp;    wp += bf_tbl;
    unsigned* e1 = (unsigned*)wp;     wp += bf_tbl;
    unsigned* e2 = (unsigned*)wp;     wp += bf_tbl;
    unsigned* e3 = (unsigned*)wp;     wp += bf_tbl;
    int2* edges = (int2*)wp;          wp += edges_bytes;
    int2* binned = (int2*)wp;         wp += edges_bytes;
    int* row_start = (int*)wp;        wp += align_up((size_t)(nrows + 1) * 4);
    int* base = (int*)wp;             wp += align_up((size_t)(nb + 1) * 4);
    int* counts = (int*)wp;           wp += align_up((size_t)(nb + 1) * 4);
    int* cursor = (int*)wp;           wp += align_up((size_t)(nb + 1) * 4);
    int* list = (int*)wp;

    // e0 bf16 conversion (+ zero bucket counts, + layer-3 row list)
    convert_kernel<<<ew_blocks, 256, 0, stream>>>(
        (const float4*)user_emb, (const float4*)item_emb,
        (uint2*)e0b, nu4, total4, counts, nb + 1,
        user_idx, pos_idx, neg_idx, list, batch, nu);

    // bucket bases via LDS histogram + single-block scan (writes cursor too)
    bucket_hist_kernel<<<1024, 256, 0, stream>>>(adj_rows, counts, nnz, nb);
    bucket_scan_kernel<<<1, 1024, 0, stream>>>(counts, base, cursor, nb);

    // LDS-staged binning, then exact CSR placement
    bin_kernel<<<(nnz + BIN_CHUNK - 1) / BIN_CHUNK, BIN_T, 0, stream>>>(
        adj_vals, adj_rows, adj_cols, cursor, binned, nnz, nb);
    place_kernel<<<nb, 512, 0, stream>>>(binned, base, edges, row_start,
                                         nrows, nb);

    const int spmm_blocks = (nrows + 3) / 4;  // 4 waves/block
    spmm_bf16_kernel<<<spmm_blocks, 256, 0, stream>>>(
        row_start, edges, (const uint4*)e0b, (uint4*)e1, nrows);
    spmm_bf16_kernel<<<spmm_blocks, 256, 0, stream>>>(
        row_start, edges, (const uint4*)e1, (uint4*)e2, nrows);
    const int nlist = 3 * batch;
    spmm_bf16_list_kernel<<<(nlist + 3) / 4, 256, 0, stream>>>(
        row_start, edges, (const uint4*)e2, (uint4*)e3, list, nlist);

    score2_kernel<<<(batch / 2 + 3) / 4, 256, 0, stream>>>(
        user_emb, item_emb, e1, e2, e3, user_idx, pos_idx, neg_idx,
        (float*)d_out, batch, nu);
  } else {
    // fallback: f32 atomic scatter path (needs 3 * nd_bytes)
    char* wp = (char*)d_ws;
    float* acc = (float*)wp;          wp += nd_bytes;
    float* e_a = (float*)wp;          wp += nd_bytes;
    float* e_b = (float*)wp;

    init_kernel<<<ew_blocks, 256, 0, stream>>>(
        (const float4*)user_emb, (const float4*)item_emb,
        (float4*)e_a, (float4*)acc, nu4, total4);
    const long long scatter_work = (long long)nnz * 64;
    const int scatter_blocks = (int)((scatter_work + 255) / 256);
    float* src = e_a;
    float* dst = e_b;
    for (int layer = 0; layer < 3; ++layer) {
      hipMemsetAsync(dst, 0, nd_bytes, stream);
      scatter_kernel<<<scatter_blocks, 256, 0, stream>>>(adj_vals, adj_rows,
                                                         adj_cols, src, dst, nnz);
      acc_kernel<<<ew_blocks, 256, 0, stream>>>((float4*)acc, (const float4*)dst,
                                                total4);
      float* t = src; src = dst; dst = t;
    }
    score_kernel<<<(batch + 3) / 4, 256, 0, stream>>>(
        acc, user_idx, pos_idx, neg_idx, (float*)d_out, batch, nu);
  }
}